// Round 1
// baseline (395.124 us; speedup 1.0000x reference)
//
#include <hip/hip_runtime.h>
#include <hip/hip_fp16.h>

#define CH 256
#define HH 96
#define WW 160
#define HW (HH * WW) // 15360

typedef _Float16 half8 __attribute__((ext_vector_type(8)));
typedef float f32x4 __attribute__((ext_vector_type(4)));

// pack two f32 -> (f16 lo, f16 hi) dword (RTN via v_cvt_f16_f32 pair)
__device__ inline unsigned pk2(float a, float b) {
    __half ha = __float2half(a);
    __half hb = __float2half(b);
    return (unsigned)__half_as_ushort(ha) | ((unsigned)__half_as_ushort(hb) << 16);
}

// WG = 256 threads = 4 waves. Tile: (b, rows y0..y0+3, cols x0..x0+15).
// Wave w handles output row y0+w for all 9 dy; 2 MFMA N-tiles cover
// S cols x0-4..x0+27. acc[9][2] = 72 VGPRs of fp32 accumulator.
__global__ __launch_bounds__(256, 2)
void corr_mfma(const float* __restrict__ Fp, const float* __restrict__ Sp,
               float* __restrict__ out) {
    // Fragment-order layouts: read addr = base + lane*16 (conflict-free b128).
    __shared__ uint4 sB[12 * 2 * 64]; // [row12][jt2][chunk(q4,n16)] : 24.5 KB
    __shared__ uint4 sA[4 * 64];      // [row4][chunk(q4,m16)]       :  4 KB

    const int bid = blockIdx.x;
    const int b   = bid & 7;       // batch-per-XCD swizzle for L2 locality
    const int rem = bid >> 3;      // 0..239
    const int y0  = (rem / 10) * 4;
    const int x0  = (rem % 10) * 16;

    const int t    = threadIdx.x;
    const int lane = t & 63;
    const int wv   = t >> 6;
    const int q    = lane >> 4;
    const int n    = lane & 15;

    const float* Fb = Fp + (size_t)b * CH * HW;
    const float* Sb = Sp + (size_t)b * CH * HW;

    unsigned* sBw = (unsigned*)sB;
    unsigned* sAw = (unsigned*)sA;

    f32x4 acc[9][2];
#pragma unroll
    for (int dy = 0; dy < 9; dy++) {
        f32x4 z = {0.f, 0.f, 0.f, 0.f};
        acc[dy][0] = z;
        acc[dy][1] = z;
    }

    for (int ch = 0; ch < 8; ch++) {
        const int c0 = ch * 32;
        __syncthreads();
        // ---- stage S: rows y0-4..y0+7, cols x0-4..x0+27, chans c0..c0+31
        // 12288 elts as (channel-pair x col-pair) quads; zero-fill OOB.
#pragma unroll
        for (int i = 0; i < 12; i++) {
            int Q    = i * 256 + t;
            int col2 = Q & 15;  // col-pair
            int hi   = Q >> 4;  // 0..191
            int row  = hi % 12;
            int c2   = hi / 12; // 0..15 channel-pair
            int col  = col2 * 2;
            int gx   = x0 - 4 + col; // even always
            int gy   = y0 - 4 + row;
            int gc   = c0 + c2 * 2;
            float2 v0 = make_float2(0.f, 0.f);
            float2 v1 = make_float2(0.f, 0.f);
            if ((unsigned)gy < HH) {
                const float* p0 = Sb + (size_t)gc * HW + gy * WW;
                if ((unsigned)gx <= (WW - 2)) {
                    v0 = *(const float2*)(p0 + gx);
                    v1 = *(const float2*)(p0 + HW + gx);
                } else {
                    if ((unsigned)gx < WW)       { v0.x = p0[gx];     v1.x = p0[HW + gx]; }
                    if ((unsigned)(gx + 1) < WW) { v0.y = p0[gx + 1]; v1.y = p0[HW + gx + 1]; }
                }
            }
            unsigned d0 = pk2(v0.x, v1.x); // col   : (c, c+1)
            unsigned d1 = pk2(v0.y, v1.y); // col+1 : (c, c+1)
            int jt = col >> 4;
            int nn = col & 15; // even, so nn+1 stays in same jt
            int qq = c2 >> 2;
            int cc = c2 & 3;
            int dw = (row * 128 + jt * 64 + qq * 16 + nn) * 4 + cc;
            sBw[dw]     = d0;
            sBw[dw + 4] = d1;
        }
        // ---- stage F: rows y0..y0+3, cols x0..x0+15 (always in bounds)
#pragma unroll
        for (int i = 0; i < 2; i++) {
            int Q    = i * 256 + t;
            int colf = (Q & 7) * 2;
            int row  = (Q >> 3) & 3;
            int c2   = Q >> 5; // 0..15
            int gc   = c0 + c2 * 2;
            const float* p0 = Fb + (size_t)gc * HW + (y0 + row) * WW + x0 + colf;
            float2 v0 = *(const float2*)p0;
            float2 v1 = *(const float2*)(p0 + HW);
            unsigned d0 = pk2(v0.x, v1.x);
            unsigned d1 = pk2(v0.y, v1.y);
            int qq = c2 >> 2;
            int cc = c2 & 3;
            int dw = (row * 64 + qq * 16 + colf) * 4 + cc;
            sAw[dw]     = d0;
            sAw[dw + 4] = d1;
        }
        __syncthreads();
        // ---- MFMA: A[m=lane&15][k=q*8+j], B[k][n=lane&15]
        half8 av = *(const half8*)(sA + wv * 64 + lane);
#pragma unroll
        for (int dy = 0; dy < 9; dy++) {
            int row  = wv + dy; // 0..11
            half8 b0 = *(const half8*)(sB + (row * 2 + 0) * 64 + lane);
            half8 b1 = *(const half8*)(sB + (row * 2 + 1) * 64 + lane);
            acc[dy][0] = __builtin_amdgcn_mfma_f32_16x16x32_f16(av, b0, acc[dy][0], 0, 0, 0);
            acc[dy][1] = __builtin_amdgcn_mfma_f32_16x16x32_f16(av, b1, acc[dy][1], 0, 0, 0);
        }
    }

    // ---- epilogue: D row m=(q*4+r), col n; dx+4 = jt*16 + n - m in [0,8].
    // Each output element has exactly one writer -> full coverage.
    const int y = y0 + wv;
#pragma unroll
    for (int r = 0; r < 4; r++) {
        const int m = q * 4 + r;
#pragma unroll
        for (int jt = 0; jt < 2; jt++) {
            const int dxp = jt * 16 + n - m;
            if (dxp >= 0 && dxp <= 8) {
                float* p = out + ((size_t)(b * 81 + dxp) * HH + y) * WW + x0 + m;
#pragma unroll
                for (int dy = 0; dy < 9; dy++) {
                    p[(size_t)dy * 9 * HW] = acc[dy][jt][r] * (1.0f / 256.0f);
                }
            }
        }
    }
}

extern "C" void kernel_launch(void* const* d_in, const int* in_sizes, int n_in,
                              void* d_out, int out_size, void* d_ws, size_t ws_size,
                              hipStream_t stream) {
    const float* F = (const float*)d_in[0];
    const float* S = (const float*)d_in[1];
    float* o = (float*)d_out;
    corr_mfma<<<dim3(1920), dim3(256), 0, stream>>>(F, S, o);
}